// Round 6
// baseline (167.441 us; speedup 1.0000x reference)
//
#include <hip/hip_runtime.h>
#include <hip/hip_cooperative_groups.h>

namespace cg = cooperative_groups;

#define NPTS 1024
#define NN (NPTS * NPTS)
#define NEDGE 32768
#define INDIM 128
#define PAD 72

typedef __attribute__((ext_vector_type(8))) short bf16x8;
typedef __attribute__((ext_vector_type(4))) float f32x4;

__device__ inline ushort f2bf(float x) {
    union { float f; unsigned u; } v; v.f = x;
    unsigned r = (v.u + 0x7FFF + ((v.u >> 16) & 1)) >> 16;
    return (ushort)r;
}

#define MFMA(a, b, c) __builtin_amdgcn_mfma_f32_16x16x32_bf16(a, b, c, 0, 0, 0)

// ==================== cooperative mega-kernel ====================
// grid 256 x 512 (1 block/CU). Phases separated by grid.sync():
//  A: zero A + zero dd + p = feat.w + b
//  B: scatter edges -> A (dense) and dd (degrees)
//  C: T0 = I, T1 = M = -(dinv_i*(A+I)_ij*dinv_j), Mbf
//  D: S = M*M -> T2 = 2S - I, Sbf            (split-K MFMA GEMM)
//  E: P = S*S -> T4; R = M*S -> T3; zero imag half
__global__ __launch_bounds__(512) void mega_kernel(
    const float* __restrict__ feat, const int* __restrict__ edges,
    const float* __restrict__ w_e1, const float* __restrict__ b_e1,
    float* __restrict__ out, float* __restrict__ A,
    ushort* __restrict__ Mbf, ushort* __restrict__ Sbf,
    float* __restrict__ p, float* __restrict__ dd, int zimag) {
    cg::grid_group grid = cg::this_grid();
    __shared__ __align__(16) ushort smem[6 * 64 * PAD];  // 54 KB

    int tid = threadIdx.x;
    int bid = blockIdx.x;
    int wid = tid >> 6, lane = tid & 63;

    // ---------- Phase A ----------
    {
        float4* A4 = (float4*)A;
#pragma unroll
        for (int i = 0; i < 2; ++i)
            A4[bid * 1024 + i * 512 + tid] = make_float4(0.f, 0.f, 0.f, 0.f);
        if (bid == 0 && tid < 256) ((float4*)dd)[tid] = make_float4(0.f, 0.f, 0.f, 0.f);
        if (wid < 4) {
            int node = bid * 4 + wid;
            const float* f = feat + node * INDIM;
            float s = f[lane] * w_e1[lane] + f[lane + 64] * w_e1[lane + 64];
#pragma unroll
            for (int off = 32; off; off >>= 1) s += __shfl_down(s, off);
            if (lane == 0) p[node] = s + b_e1[0];
        }
    }
    grid.sync();

    // ---------- Phase B ----------
    if (tid < 128) {
        int i = bid * 128 + tid;
        int u = edges[i], v = edges[NEDGE + i];
        float val = p[u] - p[v];
        if (val > 0.f) {
            float w = 1.f + val;
            atomicAdd(&A[u * NPTS + v], w);
            atomicAdd(&A[v * NPTS + u], w);
            atomicAdd(&dd[u], w);
            atomicAdd(&dd[v], w);
        } else {
            atomicAdd(&A[u * NPTS + u], 1.f);
            atomicAdd(&A[v * NPTS + v], 1.f);
            atomicAdd(&dd[u], 1.f);
            atomicAdd(&dd[v], 1.f);
        }
    }
    grid.sync();

    // ---------- Phase C ----------
    {
#pragma unroll
        for (int it = 0; it < 2; ++it) {
            int idx4 = bid * 1024 + it * 512 + tid;
            int i = idx4 >> 8;
            int j = (idx4 & 255) * 4;
            size_t idx = (size_t)idx4 * 4;
            float di = rsqrtf(dd[i] + 1.f);
            float4 a = *(const float4*)(A + idx);
            float4 d4 = *(const float4*)(dd + j);
            float4 t0 = make_float4(0.f, 0.f, 0.f, 0.f);
            if (i == j) t0.x = 1.f;
            else if (i == j + 1) t0.y = 1.f;
            else if (i == j + 2) t0.z = 1.f;
            else if (i == j + 3) t0.w = 1.f;
            a.x += (i == j);
            a.y += (i == j + 1);
            a.z += (i == j + 2);
            a.w += (i == j + 3);
            float4 m;
            m.x = -(di * a.x * rsqrtf(d4.x + 1.f));
            m.y = -(di * a.y * rsqrtf(d4.y + 1.f));
            m.z = -(di * a.z * rsqrtf(d4.z + 1.f));
            m.w = -(di * a.w * rsqrtf(d4.w + 1.f));
            *(float4*)(out + idx) = t0;
            *(float4*)(out + NN + idx) = m;
            ushort mb[4] = {f2bf(m.x), f2bf(m.y), f2bf(m.z), f2bf(m.w)};
            *(uint2*)(Mbf + idx) = *(uint2*)mb;
        }
    }
    grid.sync();

    // shared GEMM geometry
    int brow = (bid >> 4) * 64, bcol = (bid & 15) * 64;
    int r = tid >> 3, j0 = (tid & 7) * 8;
    int h = wid >> 2, w4 = wid & 3;
    int wr = (w4 & 1) * 32, wc = (w4 >> 1) * 32;
    int fr = lane & 15, g = lane >> 4;

    // ---------- Phase D: S = M*M ----------
    {
        ushort(*sA)[64][PAD] = (ushort(*)[64][PAD])smem;
        ushort(*sB)[64][PAD] = (ushort(*)[64][PAD])(smem + 2 * 64 * PAD);
        float* red = (float*)smem;

        const ushort* Arow = Mbf + (size_t)(brow + r) * NPTS;
        const ushort* Brow = Mbf + (size_t)(bcol + r) * NPTS;

        f32x4 acc[2][2] = {};
        float4 pa0 = *(const float4*)(Arow + j0);
        float4 pa1 = *(const float4*)(Arow + 64 + j0);
        float4 pb0 = *(const float4*)(Brow + j0);
        float4 pb1 = *(const float4*)(Brow + 64 + j0);

        for (int it = 0; it < 8; ++it) {
            __syncthreads();
            *(float4*)&sA[0][r][j0] = pa0;
            *(float4*)&sA[1][r][j0] = pa1;
            *(float4*)&sB[0][r][j0] = pb0;
            *(float4*)&sB[1][r][j0] = pb1;
            __syncthreads();
            if (it < 7) {
                int k0 = (it + 1) * 128;
                pa0 = *(const float4*)(Arow + k0 + j0);
                pa1 = *(const float4*)(Arow + k0 + 64 + j0);
                pb0 = *(const float4*)(Brow + k0 + j0);
                pb1 = *(const float4*)(Brow + k0 + 64 + j0);
            }
#pragma unroll
            for (int kc = 0; kc < 2; ++kc) {
                int kk = kc * 32 + g * 8;
                bf16x8 a0 = *(const bf16x8*)&sA[h][wr + fr][kk];
                bf16x8 a1 = *(const bf16x8*)&sA[h][wr + 16 + fr][kk];
                bf16x8 b0 = *(const bf16x8*)&sB[h][wc + fr][kk];
                bf16x8 b1 = *(const bf16x8*)&sB[h][wc + 16 + fr][kk];
                acc[0][0] = MFMA(a0, b0, acc[0][0]);
                acc[0][1] = MFMA(a0, b1, acc[0][1]);
                acc[1][0] = MFMA(a1, b0, acc[1][0]);
                acc[1][1] = MFMA(a1, b1, acc[1][1]);
            }
        }

        __syncthreads();
        if (h == 1) {
#pragma unroll
            for (int q = 0; q < 4; ++q)
                *(f32x4*)&red[q * 1024 + (w4 * 64 + lane) * 4] = acc[q >> 1][q & 1];
        }
        __syncthreads();
        if (h == 0) {
            float* T2 = out + (size_t)2 * NN;
#pragma unroll
            for (int mi = 0; mi < 2; ++mi) {
#pragma unroll
                for (int ni = 0; ni < 2; ++ni) {
                    f32x4 o = *(f32x4*)&red[(mi * 2 + ni) * 1024 + (w4 * 64 + lane) * 4];
#pragma unroll
                    for (int q = 0; q < 4; ++q) {
                        int row = brow + wr + mi * 16 + g * 4 + q;
                        int col = bcol + wc + ni * 16 + fr;
                        size_t idx = (size_t)row * NPTS + col;
                        float s = acc[mi][ni][q] + o[q];
                        T2[idx] = 2.f * s - (row == col ? 1.f : 0.f);
                        Sbf[idx] = f2bf(s);
                    }
                }
            }
        }
    }
    grid.sync();

    // ---------- Phase E: P = S*S -> T4, R = M*S -> T3, zero imag ----------
    {
        if (zimag) {
            float4* z = (float4*)(out + (size_t)5 * NN) + (size_t)bid * 5120 + tid;
#pragma unroll
            for (int i = 0; i < 10; ++i) z[i * 512] = make_float4(0.f, 0.f, 0.f, 0.f);
        }

        ushort(*sAS)[64][PAD] = (ushort(*)[64][PAD])smem;
        ushort(*sAM)[64][PAD] = (ushort(*)[64][PAD])(smem + 2 * 64 * PAD);
        ushort(*sB)[64][PAD] = (ushort(*)[64][PAD])(smem + 4 * 64 * PAD);
        float* red = (float*)smem;

        const ushort* ASrow = Sbf + (size_t)(brow + r) * NPTS;
        const ushort* AMrow = Mbf + (size_t)(brow + r) * NPTS;
        const ushort* Brow = Sbf + (size_t)(bcol + r) * NPTS;

        f32x4 accP[2][2] = {};
        f32x4 accR[2][2] = {};
        float4 ps0 = *(const float4*)(ASrow + j0);
        float4 ps1 = *(const float4*)(ASrow + 64 + j0);
        float4 pm0 = *(const float4*)(AMrow + j0);
        float4 pm1 = *(const float4*)(AMrow + 64 + j0);
        float4 pb0 = *(const float4*)(Brow + j0);
        float4 pb1 = *(const float4*)(Brow + 64 + j0);

        for (int it = 0; it < 8; ++it) {
            __syncthreads();
            *(float4*)&sAS[0][r][j0] = ps0;
            *(float4*)&sAS[1][r][j0] = ps1;
            *(float4*)&sAM[0][r][j0] = pm0;
            *(float4*)&sAM[1][r][j0] = pm1;
            *(float4*)&sB[0][r][j0] = pb0;
            *(float4*)&sB[1][r][j0] = pb1;
            __syncthreads();
            if (it < 7) {
                int k0 = (it + 1) * 128;
                ps0 = *(const float4*)(ASrow + k0 + j0);
                ps1 = *(const float4*)(ASrow + k0 + 64 + j0);
                pm0 = *(const float4*)(AMrow + k0 + j0);
                pm1 = *(const float4*)(AMrow + k0 + 64 + j0);
                pb0 = *(const float4*)(Brow + k0 + j0);
                pb1 = *(const float4*)(Brow + k0 + 64 + j0);
            }
#pragma unroll
            for (int kc = 0; kc < 2; ++kc) {
                int kk = kc * 32 + g * 8;
                bf16x8 b0 = *(const bf16x8*)&sB[h][wc + fr][kk];
                bf16x8 b1 = *(const bf16x8*)&sB[h][wc + 16 + fr][kk];
                bf16x8 s0 = *(const bf16x8*)&sAS[h][wr + fr][kk];
                bf16x8 s1 = *(const bf16x8*)&sAS[h][wr + 16 + fr][kk];
                accP[0][0] = MFMA(s0, b0, accP[0][0]);
                accP[0][1] = MFMA(s0, b1, accP[0][1]);
                accP[1][0] = MFMA(s1, b0, accP[1][0]);
                accP[1][1] = MFMA(s1, b1, accP[1][1]);
                bf16x8 m0 = *(const bf16x8*)&sAM[h][wr + fr][kk];
                bf16x8 m1 = *(const bf16x8*)&sAM[h][wr + 16 + fr][kk];
                accR[0][0] = MFMA(m0, b0, accR[0][0]);
                accR[0][1] = MFMA(m0, b1, accR[0][1]);
                accR[1][0] = MFMA(m1, b0, accR[1][0]);
                accR[1][1] = MFMA(m1, b1, accR[1][1]);
            }
        }

        __syncthreads();
        if (h == 1) {
#pragma unroll
            for (int q = 0; q < 4; ++q) {
                *(f32x4*)&red[q * 1024 + (w4 * 64 + lane) * 4] = accP[q >> 1][q & 1];
                *(f32x4*)&red[4096 + q * 1024 + (w4 * 64 + lane) * 4] = accR[q >> 1][q & 1];
            }
        }
        __syncthreads();
        if (h == 0) {
            float* T1 = out + (size_t)NN;
            float* T2 = out + (size_t)2 * NN;
            float* T3 = out + (size_t)3 * NN;
            float* T4 = out + (size_t)4 * NN;
#pragma unroll
            for (int mi = 0; mi < 2; ++mi) {
#pragma unroll
                for (int ni = 0; ni < 2; ++ni) {
                    f32x4 oP = *(f32x4*)&red[(mi * 2 + ni) * 1024 + (w4 * 64 + lane) * 4];
                    f32x4 oR = *(f32x4*)&red[4096 + (mi * 2 + ni) * 1024 + (w4 * 64 + lane) * 4];
#pragma unroll
                    for (int q = 0; q < 4; ++q) {
                        int row = brow + wr + mi * 16 + g * 4 + q;
                        int col = bcol + wc + ni * 16 + fr;
                        size_t idx = (size_t)row * NPTS + col;
                        float sp = accP[mi][ni][q] + oP[q];
                        float sr = accR[mi][ni][q] + oR[q];
                        T4[idx] = 8.f * sp - 4.f * T2[idx] - (row == col ? 3.f : 0.f);
                        T3[idx] = 4.f * sr - 3.f * T1[idx];
                    }
                }
            }
        }
    }
}

// ==================== fallback path (R5 kernels) ====================

__global__ void zeroA_p_kernel(float4* __restrict__ A4,
                               const float* __restrict__ feat,
                               const float* __restrict__ w,
                               const float* __restrict__ b,
                               float* __restrict__ p) {
    int t = threadIdx.x;
    A4[blockIdx.x * 256 + t] = make_float4(0.f, 0.f, 0.f, 0.f);
    if (blockIdx.x < 256) {
        int wid = t >> 6, lane = t & 63;
        int node = blockIdx.x * 4 + wid;
        const float* f = feat + node * INDIM;
        float s = f[lane] * w[lane] + f[lane + 64] * w[lane + 64];
#pragma unroll
        for (int off = 32; off; off >>= 1) s += __shfl_down(s, off);
        if (lane == 0) p[node] = s + b[0];
    }
}

__global__ void build_A_kernel(const int* __restrict__ eu, const int* __restrict__ ev,
                               const float* __restrict__ p, float* __restrict__ A,
                               float* __restrict__ dd) {
    int i = blockIdx.x * blockDim.x + threadIdx.x;
    if (i >= NEDGE) return;
    int u = eu[i], v = ev[i];
    float val = p[u] - p[v];
    if (val > 0.f) {
        float w = 1.f + val;
        atomicAdd(&A[u * NPTS + v], w);
        atomicAdd(&A[v * NPTS + u], w);
        atomicAdd(&dd[u], w);
        atomicAdd(&dd[v], w);
    } else {
        atomicAdd(&A[u * NPTS + u], 1.f);
        atomicAdd(&A[v * NPTS + v], 1.f);
        atomicAdd(&dd[u], 1.f);
        atomicAdd(&dd[v], 1.f);
    }
}

__global__ void zero_d_kernel(float4* __restrict__ d4) {
    if (blockIdx.x == 0 && threadIdx.x < 256) d4[threadIdx.x] = make_float4(0.f, 0.f, 0.f, 0.f);
}

__global__ void normalize_kernel(const float* __restrict__ A, const float* __restrict__ dd,
                                 float* __restrict__ out, ushort* __restrict__ Mbf) {
    int idx4 = blockIdx.x * blockDim.x + threadIdx.x;
    int i = idx4 >> 8;
    int j = (idx4 & 255) * 4;
    size_t idx = (size_t)idx4 * 4;
    float di = rsqrtf(dd[i] + 1.f);
    float4 a = *(const float4*)(A + idx);
    float4 d4 = *(const float4*)(dd + j);
    float4 t0 = make_float4(0.f, 0.f, 0.f, 0.f);
    if (i == j) t0.x = 1.f;
    else if (i == j + 1) t0.y = 1.f;
    else if (i == j + 2) t0.z = 1.f;
    else if (i == j + 3) t0.w = 1.f;
    a.x += (i == j);
    a.y += (i == j + 1);
    a.z += (i == j + 2);
    a.w += (i == j + 3);
    float4 m;
    m.x = -(di * a.x * rsqrtf(d4.x + 1.f));
    m.y = -(di * a.y * rsqrtf(d4.y + 1.f));
    m.z = -(di * a.z * rsqrtf(d4.z + 1.f));
    m.w = -(di * a.w * rsqrtf(d4.w + 1.f));
    *(float4*)(out + idx) = t0;
    *(float4*)(out + NN + idx) = m;
    ushort mb[4] = {f2bf(m.x), f2bf(m.y), f2bf(m.z), f2bf(m.w)};
    *(uint2*)(Mbf + idx) = *(uint2*)mb;
}

__global__ __launch_bounds__(512) void gemm_S_kernel(const ushort* __restrict__ Mbf,
                                                     ushort* __restrict__ Sbf,
                                                     float* __restrict__ out) {
    __shared__ __align__(16) ushort smem[4 * 64 * PAD];
    ushort(*sA)[64][PAD] = (ushort(*)[64][PAD])smem;
    ushort(*sB)[64][PAD] = (ushort(*)[64][PAD])(smem + 2 * 64 * PAD);
    float* red = (float*)smem;

    int tid = threadIdx.x;
    int brow = blockIdx.y * 64, bcol = blockIdx.x * 64;
    int r = tid >> 3, j0 = (tid & 7) * 8;
    int wid = tid >> 6, lane = tid & 63;
    int h = wid >> 2, w4 = wid & 3;
    int wr = (w4 & 1) * 32, wc = (w4 >> 1) * 32;
    int fr = lane & 15, g = lane >> 4;

    const ushort* Arow = Mbf + (size_t)(brow + r) * NPTS;
    const ushort* Brow = Mbf + (size_t)(bcol + r) * NPTS;

    f32x4 acc[2][2] = {};
    float4 pa0 = *(const float4*)(Arow + j0);
    float4 pa1 = *(const float4*)(Arow + 64 + j0);
    float4 pb0 = *(const float4*)(Brow + j0);
    float4 pb1 = *(const float4*)(Brow + 64 + j0);

    for (int it = 0; it < 8; ++it) {
        __syncthreads();
        *(float4*)&sA[0][r][j0] = pa0;
        *(float4*)&sA[1][r][j0] = pa1;
        *(float4*)&sB[0][r][j0] = pb0;
        *(float4*)&sB[1][r][j0] = pb1;
        __syncthreads();
        if (it < 7) {
            int k0 = (it + 1) * 128;
            pa0 = *(const float4*)(Arow + k0 + j0);
            pa1 = *(const float4*)(Arow + k0 + 64 + j0);
            pb0 = *(const float4*)(Brow + k0 + j0);
            pb1 = *(const float4*)(Brow + k0 + 64 + j0);
        }
#pragma unroll
        for (int kc = 0; kc < 2; ++kc) {
            int kk = kc * 32 + g * 8;
            bf16x8 a0 = *(const bf16x8*)&sA[h][wr + fr][kk];
            bf16x8 a1 = *(const bf16x8*)&sA[h][wr + 16 + fr][kk];
            bf16x8 b0 = *(const bf16x8*)&sB[h][wc + fr][kk];
            bf16x8 b1 = *(const bf16x8*)&sB[h][wc + 16 + fr][kk];
            acc[0][0] = MFMA(a0, b0, acc[0][0]);
            acc[0][1] = MFMA(a0, b1, acc[0][1]);
            acc[1][0] = MFMA(a1, b0, acc[1][0]);
            acc[1][1] = MFMA(a1, b1, acc[1][1]);
        }
    }

    __syncthreads();
    if (h == 1) {
#pragma unroll
        for (int q = 0; q < 4; ++q)
            *(f32x4*)&red[q * 1024 + (w4 * 64 + lane) * 4] = acc[q >> 1][q & 1];
    }
    __syncthreads();
    if (h == 0) {
        float* T2 = out + (size_t)2 * NN;
#pragma unroll
        for (int mi = 0; mi < 2; ++mi) {
#pragma unroll
            for (int ni = 0; ni < 2; ++ni) {
                f32x4 o = *(f32x4*)&red[(mi * 2 + ni) * 1024 + (w4 * 64 + lane) * 4];
#pragma unroll
                for (int q = 0; q < 4; ++q) {
                    int row = brow + wr + mi * 16 + g * 4 + q;
                    int col = bcol + wc + ni * 16 + fr;
                    size_t idx = (size_t)row * NPTS + col;
                    float s = acc[mi][ni][q] + o[q];
                    T2[idx] = 2.f * s - (row == col ? 1.f : 0.f);
                    Sbf[idx] = f2bf(s);
                }
            }
        }
    }
}

__global__ __launch_bounds__(512) void gemm_T34_kernel(const ushort* __restrict__ Mbf,
                                                       const ushort* __restrict__ Sbf,
                                                       float* __restrict__ out,
                                                       int zimag) {
    if (zimag) {
        int bid = blockIdx.y * 16 + blockIdx.x;
        float4* z = (float4*)(out + (size_t)5 * NN) + (size_t)bid * 5120 + threadIdx.x;
#pragma unroll
        for (int i = 0; i < 10; ++i) z[i * 512] = make_float4(0.f, 0.f, 0.f, 0.f);
    }

    __shared__ __align__(16) ushort smem[6 * 64 * PAD];
    ushort(*sAS)[64][PAD] = (ushort(*)[64][PAD])smem;
    ushort(*sAM)[64][PAD] = (ushort(*)[64][PAD])(smem + 2 * 64 * PAD);
    ushort(*sB)[64][PAD] = (ushort(*)[64][PAD])(smem + 4 * 64 * PAD);
    float* red = (float*)smem;

    int tid = threadIdx.x;
    int brow = blockIdx.y * 64, bcol = blockIdx.x * 64;
    int r = tid >> 3, j0 = (tid & 7) * 8;
    int wid = tid >> 6, lane = tid & 63;
    int h = wid >> 2, w4 = wid & 3;
    int wr = (w4 & 1) * 32, wc = (w4 >> 1) * 32;
    int fr = lane & 15, g = lane >> 4;

    const ushort* ASrow = Sbf + (size_t)(brow + r) * NPTS;
    const ushort* AMrow = Mbf + (size_t)(brow + r) * NPTS;
    const ushort* Brow = Sbf + (size_t)(bcol + r) * NPTS;

    f32x4 accP[2][2] = {};
    f32x4 accR[2][2] = {};
    float4 ps0 = *(const float4*)(ASrow + j0);
    float4 ps1 = *(const float4*)(ASrow + 64 + j0);
    float4 pm0 = *(const float4*)(AMrow + j0);
    float4 pm1 = *(const float4*)(AMrow + 64 + j0);
    float4 pb0 = *(const float4*)(Brow + j0);
    float4 pb1 = *(const float4*)(Brow + 64 + j0);

    for (int it = 0; it < 8; ++it) {
        __syncthreads();
        *(float4*)&sAS[0][r][j0] = ps0;
        *(float4*)&sAS[1][r][j0] = ps1;
        *(float4*)&sAM[0][r][j0] = pm0;
        *(float4*)&sAM[1][r][j0] = pm1;
        *(float4*)&sB[0][r][j0] = pb0;
        *(float4*)&sB[1][r][j0] = pb1;
        __syncthreads();
        if (it < 7) {
            int k0 = (it + 1) * 128;
            ps0 = *(const float4*)(ASrow + k0 + j0);
            ps1 = *(const float4*)(ASrow + k0 + 64 + j0);
            pm0 = *(const float4*)(AMrow + k0 + j0);
            pm1 = *(const float4*)(AMrow + k0 + 64 + j0);
            pb0 = *(const float4*)(Brow + k0 + j0);
            pb1 = *(const float4*)(Brow + k0 + 64 + j0);
        }
#pragma unroll
        for (int kc = 0; kc < 2; ++kc) {
            int kk = kc * 32 + g * 8;
            bf16x8 b0 = *(const bf16x8*)&sB[h][wc + fr][kk];
            bf16x8 b1 = *(const bf16x8*)&sB[h][wc + 16 + fr][kk];
            bf16x8 s0 = *(const bf16x8*)&sAS[h][wr + fr][kk];
            bf16x8 s1 = *(const bf16x8*)&sAS[h][wr + 16 + fr][kk];
            accP[0][0] = MFMA(s0, b0, accP[0][0]);
            accP[0][1] = MFMA(s0, b1, accP[0][1]);
            accP[1][0] = MFMA(s1, b0, accP[1][0]);
            accP[1][1] = MFMA(s1, b1, accP[1][1]);
            bf16x8 m0 = *(const bf16x8*)&sAM[h][wr + fr][kk];
            bf16x8 m1 = *(const bf16x8*)&sAM[h][wr + 16 + fr][kk];
            accR[0][0] = MFMA(m0, b0, accR[0][0]);
            accR[0][1] = MFMA(m0, b1, accR[0][1]);
            accR[1][0] = MFMA(m1, b0, accR[1][0]);
            accR[1][1] = MFMA(m1, b1, accR[1][1]);
        }
    }

    __syncthreads();
    if (h == 1) {
#pragma unroll
        for (int q = 0; q < 4; ++q) {
            *(f32x4*)&red[q * 1024 + (w4 * 64 + lane) * 4] = accP[q >> 1][q & 1];
            *(f32x4*)&red[4096 + q * 1024 + (w4 * 64 + lane) * 4] = accR[q >> 1][q & 1];
        }
    }
    __syncthreads();
    if (h == 0) {
        float* T1 = out + (size_t)NN;
        float* T2 = out + (size_t)2 * NN;
        float* T3 = out + (size_t)3 * NN;
        float* T4 = out + (size_t)4 * NN;
#pragma unroll
        for (int mi = 0; mi < 2; ++mi) {
#pragma unroll
            for (int ni = 0; ni < 2; ++ni) {
                f32x4 oP = *(f32x4*)&red[(mi * 2 + ni) * 1024 + (w4 * 64 + lane) * 4];
                f32x4 oR = *(f32x4*)&red[4096 + (mi * 2 + ni) * 1024 + (w4 * 64 + lane) * 4];
#pragma unroll
                for (int q = 0; q < 4; ++q) {
                    int row = brow + wr + mi * 16 + g * 4 + q;
                    int col = bcol + wc + ni * 16 + fr;
                    size_t idx = (size_t)row * NPTS + col;
                    float sp = accP[mi][ni][q] + oP[q];
                    float sr = accR[mi][ni][q] + oR[q];
                    T4[idx] = 8.f * sp - 4.f * T2[idx] - (row == col ? 3.f : 0.f);
                    T3[idx] = 4.f * sr - 3.f * T1[idx];
                }
            }
        }
    }
}

__global__ void zero_kernel(float4* __restrict__ p, int n4) {
    int i = blockIdx.x * blockDim.x + threadIdx.x;
    if (i < n4) p[i] = make_float4(0.f, 0.f, 0.f, 0.f);
}

// ==================== launch ====================

extern "C" void kernel_launch(void* const* d_in, const int* in_sizes, int n_in,
                              void* d_out, int out_size, void* d_ws, size_t ws_size,
                              hipStream_t stream) {
    const float* feat = (const float*)d_in[0];
    const int* edges = (const int*)d_in[1];
    const float* w_e1 = (const float*)d_in[2];
    const float* b_e1 = (const float*)d_in[3];
    float* out = (float*)d_out;

    const size_t need = (size_t)NN * 4 + (size_t)NN * 2 + (size_t)NN * 2 + NPTS * 8 + 256;
    float* A;
    ushort* Mbf;
    ushort* Sbf;
    float* p;
    float* dd;
    int use_ws = (ws_size >= need);
    if (use_ws) {
        char* w = (char*)d_ws;
        A = (float*)w;        w += (size_t)NN * 4;
        Mbf = (ushort*)w;     w += (size_t)NN * 2;
        Sbf = (ushort*)w;     w += (size_t)NN * 2;
        p = (float*)w;        w += NPTS * 4;
        dd = (float*)w;
    } else {
        A = out + (size_t)5 * NN;
        Mbf = (ushort*)(out + (size_t)6 * NN);
        Sbf = Mbf + NN;
        p = out + (size_t)7 * NN;
        dd = p + NPTS;
    }

    // single cooperative mega-kernel (5 phases, 4 grid syncs)
    void* kargs[] = {(void*)&feat, (void*)&edges, (void*)&w_e1, (void*)&b_e1,
                     (void*)&out, (void*)&A, (void*)&Mbf, (void*)&Sbf,
                     (void*)&p, (void*)&dd, (void*)&use_ws};
    hipError_t err = hipLaunchCooperativeKernel((void*)mega_kernel, dim3(256), dim3(512),
                                                kargs, 0, stream);
    if (err == hipSuccess) {
        if (!use_ws) {
            zero_kernel<<<(5 * NN / 4 + 255) / 256, 256, 0, stream>>>(
                (float4*)(out + (size_t)5 * NN), 5 * NN / 4);
        }
        return;
    }

    // fallback: proven multi-launch path
    zeroA_p_kernel<<<1024, 256, 0, stream>>>((float4*)A, feat, w_e1, b_e1, p);
    zero_d_kernel<<<1, 256, 0, stream>>>((float4*)dd);
    build_A_kernel<<<(NEDGE + 255) / 256, 256, 0, stream>>>(edges, edges + NEDGE, p, A, dd);
    normalize_kernel<<<NN / 4 / 256, 256, 0, stream>>>(A, dd, out, Mbf);

    dim3 grid(16, 16);
    gemm_S_kernel<<<grid, 512, 0, stream>>>(Mbf, Sbf, out);
    gemm_T34_kernel<<<grid, 512, 0, stream>>>(Mbf, Sbf, out, use_ws);

    if (!use_ws) {
        zero_kernel<<<(5 * NN / 4 + 255) / 256, 256, 0, stream>>>(
            (float4*)(out + (size_t)5 * NN), 5 * NN / 4);
    }
}

// Round 7
// 59.107 us; speedup vs baseline: 2.8329x; 2.8329x over previous
//
#include <hip/hip_runtime.h>

#define NPTS 1024
#define NN (NPTS * NPTS)
#define NEDGE 32768
#define INDIM 128
#define PAD 72

typedef __attribute__((ext_vector_type(8))) short bf16x8;
typedef __attribute__((ext_vector_type(4))) float f32x4;

__device__ inline ushort f2bf(float x) {
    union { float f; unsigned u; } v; v.f = x;
    unsigned r = (v.u + 0x7FFF + ((v.u >> 16) & 1)) >> 16;
    return (ushort)r;
}

#define MFMA(a, b, c) __builtin_amdgcn_mfma_f32_16x16x32_bf16(a, b, c, 0, 0, 0)

// ---------------- front-end kernels ----------------

// grid 1024 x 256: zero A; blocks 0..255 also compute p (one wave per node);
// block 0 zeroes dd.
__global__ void zeroA_p_kernel(float4* __restrict__ A4,
                               const float* __restrict__ feat,
                               const float* __restrict__ w,
                               const float* __restrict__ b,
                               float* __restrict__ p,
                               float4* __restrict__ dd4) {
    int t = threadIdx.x;
    A4[blockIdx.x * 256 + t] = make_float4(0.f, 0.f, 0.f, 0.f);
    if (blockIdx.x == 1024 - 1 && t < 256) dd4[t] = make_float4(0.f, 0.f, 0.f, 0.f);
    if (blockIdx.x < 256) {
        int wid = t >> 6, lane = t & 63;
        int node = blockIdx.x * 4 + wid;
        const float* f = feat + node * INDIM;
        float s = f[lane] * w[lane] + f[lane + 64] * w[lane + 64];
#pragma unroll
        for (int off = 32; off; off >>= 1) s += __shfl_down(s, off);
        if (lane == 0) p[node] = s + b[0];
    }
}

// scatter edges into A and accumulate degrees dd
__global__ void build_A_kernel(const int* __restrict__ eu, const int* __restrict__ ev,
                               const float* __restrict__ p, float* __restrict__ A,
                               float* __restrict__ dd) {
    int i = blockIdx.x * blockDim.x + threadIdx.x;
    if (i >= NEDGE) return;
    int u = eu[i], v = ev[i];
    float val = p[u] - p[v];
    if (val > 0.f) {
        float w = 1.f + val;
        atomicAdd(&A[u * NPTS + v], w);
        atomicAdd(&A[v * NPTS + u], w);
        atomicAdd(&dd[u], w);
        atomicAdd(&dd[v], w);
    } else {
        atomicAdd(&A[u * NPTS + u], 1.f);
        atomicAdd(&A[v * NPTS + v], 1.f);
        atomicAdd(&dd[u], 1.f);
        atomicAdd(&dd[v], 1.f);
    }
}

// T0 = I, T1 = M = -(dinv_i*(A+I)_ij*dinv_j), Mbf = bf16(M); dinv = rsqrt(dd+1)
__global__ void normalize_kernel(const float* __restrict__ A, const float* __restrict__ dd,
                                 float* __restrict__ out, ushort* __restrict__ Mbf) {
    int idx4 = blockIdx.x * blockDim.x + threadIdx.x;
    int i = idx4 >> 8;
    int j = (idx4 & 255) * 4;
    size_t idx = (size_t)idx4 * 4;
    float di = rsqrtf(dd[i] + 1.f);
    float4 a = *(const float4*)(A + idx);
    float4 d4 = *(const float4*)(dd + j);
    float4 t0 = make_float4(0.f, 0.f, 0.f, 0.f);
    if (i == j) t0.x = 1.f;
    else if (i == j + 1) t0.y = 1.f;
    else if (i == j + 2) t0.z = 1.f;
    else if (i == j + 3) t0.w = 1.f;
    a.x += (i == j);
    a.y += (i == j + 1);
    a.z += (i == j + 2);
    a.w += (i == j + 3);
    float4 m;
    m.x = -(di * a.x * rsqrtf(d4.x + 1.f));
    m.y = -(di * a.y * rsqrtf(d4.y + 1.f));
    m.z = -(di * a.z * rsqrtf(d4.z + 1.f));
    m.w = -(di * a.w * rsqrtf(d4.w + 1.f));
    *(float4*)(out + idx) = t0;
    *(float4*)(out + NN + idx) = m;
    ushort mb[4] = {f2bf(m.x), f2bf(m.y), f2bf(m.z), f2bf(m.w)};
    *(uint2*)(Mbf + idx) = *(uint2*)mb;
}

// ---------------- MFMA GEMMs: double-buffered LDS, ONE barrier per K-step ----
// 64x64 tile / block, 512 thr = 8 waves; wave owns 16x32 (wr=(wid&3)*16,
// wc=(wid>>2)*32). BK=64, 16 iterations. Loop body:
//   sync; ds_write buf[(t+1)&1] (tile t+1 regs); global prefetch tile t+2;
//   MFMA from buf[t&1].
// The single sync covers both "buf[t&1] written" and "readers of the buffer
// being overwritten (used at t-1) are drained".

// phase 0: S = M*M -> T2 = 2S - I, Sbf = bf16(S)
__global__ __launch_bounds__(512) void gemm_S_kernel(const ushort* __restrict__ Mbf,
                                                     ushort* __restrict__ Sbf,
                                                     float* __restrict__ out) {
    __shared__ __align__(16) ushort sA[2][64][PAD];
    __shared__ __align__(16) ushort sB[2][64][PAD];

    int tid = threadIdx.x;
    int brow = blockIdx.y * 64, bcol = blockIdx.x * 64;
    int r = tid >> 3, j0 = (tid & 7) * 8;
    int wid = tid >> 6, lane = tid & 63;
    int wr = (wid & 3) * 16, wc = (wid >> 2) * 32;
    int fr = lane & 15, g = lane >> 4;

    const ushort* Arow = Mbf + (size_t)(brow + r) * NPTS;
    const ushort* Brow = Mbf + (size_t)(bcol + r) * NPTS;

    f32x4 acc[2] = {};
    // prologue: tile0 -> buf0; prefetch tile1
    float4 pa = *(const float4*)(Arow + j0);
    float4 pb = *(const float4*)(Brow + j0);
    *(float4*)&sA[0][r][j0] = pa;
    *(float4*)&sB[0][r][j0] = pb;
    pa = *(const float4*)(Arow + 64 + j0);
    pb = *(const float4*)(Brow + 64 + j0);

    const int NT = NPTS / 64;
    for (int t = 0; t < NT; ++t) {
        __syncthreads();
        if (t + 1 < NT) {
            *(float4*)&sA[(t + 1) & 1][r][j0] = pa;
            *(float4*)&sB[(t + 1) & 1][r][j0] = pb;
        }
        if (t + 2 < NT) {
            pa = *(const float4*)(Arow + (t + 2) * 64 + j0);
            pb = *(const float4*)(Brow + (t + 2) * 64 + j0);
        }
        int cb = t & 1;
#pragma unroll
        for (int kc = 0; kc < 2; ++kc) {
            int kk = kc * 32 + g * 8;
            bf16x8 a0 = *(const bf16x8*)&sA[cb][wr + fr][kk];
            bf16x8 b0 = *(const bf16x8*)&sB[cb][wc + fr][kk];
            bf16x8 b1 = *(const bf16x8*)&sB[cb][wc + 16 + fr][kk];
            acc[0] = MFMA(a0, b0, acc[0]);
            acc[1] = MFMA(a0, b1, acc[1]);
        }
    }

    float* T2 = out + (size_t)2 * NN;
#pragma unroll
    for (int ni = 0; ni < 2; ++ni) {
#pragma unroll
        for (int q = 0; q < 4; ++q) {
            int row = brow + wr + g * 4 + q;
            int col = bcol + wc + ni * 16 + fr;
            size_t idx = (size_t)row * NPTS + col;
            float s = acc[ni][q];
            T2[idx] = 2.f * s - (row == col ? 1.f : 0.f);
            Sbf[idx] = f2bf(s);
        }
    }
}

// phase 1 (fused): P = S*S -> T4 = 8P - 4*T2 - 3I;  R = M*S -> T3 = 4R - 3*T1
__global__ __launch_bounds__(512) void gemm_T34_kernel(const ushort* __restrict__ Mbf,
                                                       const ushort* __restrict__ Sbf,
                                                       float* __restrict__ out,
                                                       int zimag) {
    // hidden zeroing of the imag half (20 MB over 256 blocks)
    if (zimag) {
        int bid = blockIdx.y * 16 + blockIdx.x;
        float4* z = (float4*)(out + (size_t)5 * NN) + (size_t)bid * 5120 + threadIdx.x;
#pragma unroll
        for (int i = 0; i < 10; ++i) z[i * 512] = make_float4(0.f, 0.f, 0.f, 0.f);
    }

    __shared__ __align__(16) ushort sAS[2][64][PAD];
    __shared__ __align__(16) ushort sAM[2][64][PAD];
    __shared__ __align__(16) ushort sB[2][64][PAD];

    int tid = threadIdx.x;
    int brow = blockIdx.y * 64, bcol = blockIdx.x * 64;
    int r = tid >> 3, j0 = (tid & 7) * 8;
    int wid = tid >> 6, lane = tid & 63;
    int wr = (wid & 3) * 16, wc = (wid >> 2) * 32;
    int fr = lane & 15, g = lane >> 4;

    const ushort* ASrow = Sbf + (size_t)(brow + r) * NPTS;
    const ushort* AMrow = Mbf + (size_t)(brow + r) * NPTS;
    const ushort* Brow = Sbf + (size_t)(bcol + r) * NPTS;

    f32x4 accP[2] = {};
    f32x4 accR[2] = {};
    float4 ps = *(const float4*)(ASrow + j0);
    float4 pm = *(const float4*)(AMrow + j0);
    float4 pb = *(const float4*)(Brow + j0);
    *(float4*)&sAS[0][r][j0] = ps;
    *(float4*)&sAM[0][r][j0] = pm;
    *(float4*)&sB[0][r][j0] = pb;
    ps = *(const float4*)(ASrow + 64 + j0);
    pm = *(const float4*)(AMrow + 64 + j0);
    pb = *(const float4*)(Brow + 64 + j0);

    const int NT = NPTS / 64;
    for (int t = 0; t < NT; ++t) {
        __syncthreads();
        if (t + 1 < NT) {
            *(float4*)&sAS[(t + 1) & 1][r][j0] = ps;
            *(float4*)&sAM[(t + 1) & 1][r][j0] = pm;
            *(float4*)&sB[(t + 1) & 1][r][j0] = pb;
        }
        if (t + 2 < NT) {
            int k0 = (t + 2) * 64;
            ps = *(const float4*)(ASrow + k0 + j0);
            pm = *(const float4*)(AMrow + k0 + j0);
            pb = *(const float4*)(Brow + k0 + j0);
        }
        int cb = t & 1;
#pragma unroll
        for (int kc = 0; kc < 2; ++kc) {
            int kk = kc * 32 + g * 8;
            bf16x8 b0 = *(const bf16x8*)&sB[cb][wc + fr][kk];
            bf16x8 b1 = *(const bf16x8*)&sB[cb][wc + 16 + fr][kk];
            bf16x8 s0 = *(const bf16x8*)&sAS[cb][wr + fr][kk];
            bf16x8 m0 = *(const bf16x8*)&sAM[cb][wr + fr][kk];
            accP[0] = MFMA(s0, b0, accP[0]);
            accP[1] = MFMA(s0, b1, accP[1]);
            accR[0] = MFMA(m0, b0, accR[0]);
            accR[1] = MFMA(m0, b1, accR[1]);
        }
    }

    float* T1 = out + (size_t)NN;
    float* T2 = out + (size_t)2 * NN;
    float* T3 = out + (size_t)3 * NN;
    float* T4 = out + (size_t)4 * NN;
#pragma unroll
    for (int ni = 0; ni < 2; ++ni) {
#pragma unroll
        for (int q = 0; q < 4; ++q) {
            int row = brow + wr + g * 4 + q;
            int col = bcol + wc + ni * 16 + fr;
            size_t idx = (size_t)row * NPTS + col;
            float sp = accP[ni][q];
            float sr = accR[ni][q];
            T4[idx] = 8.f * sp - 4.f * T2[idx] - (row == col ? 3.f : 0.f);
            T3[idx] = 4.f * sr - 3.f * T1[idx];
        }
    }
}

__global__ void zero_kernel(float4* __restrict__ p, int n4) {
    int i = blockIdx.x * blockDim.x + threadIdx.x;
    if (i < n4) p[i] = make_float4(0.f, 0.f, 0.f, 0.f);
}

// ---------------- launch ----------------

extern "C" void kernel_launch(void* const* d_in, const int* in_sizes, int n_in,
                              void* d_out, int out_size, void* d_ws, size_t ws_size,
                              hipStream_t stream) {
    const float* feat = (const float*)d_in[0];
    const int* edges = (const int*)d_in[1];
    const float* w_e1 = (const float*)d_in[2];
    const float* b_e1 = (const float*)d_in[3];
    float* out = (float*)d_out;

    const size_t need = (size_t)NN * 4 + (size_t)NN * 2 + (size_t)NN * 2 + NPTS * 8 + 256;
    float* A;
    ushort* Mbf;
    ushort* Sbf;
    float* p;
    float* dd;
    int use_ws = (ws_size >= need);
    if (use_ws) {
        char* w = (char*)d_ws;
        A = (float*)w;        w += (size_t)NN * 4;
        Mbf = (ushort*)w;     w += (size_t)NN * 2;
        Sbf = (ushort*)w;     w += (size_t)NN * 2;
        p = (float*)w;        w += NPTS * 4;
        dd = (float*)w;
    } else {
        A = out + (size_t)5 * NN;
        Mbf = (ushort*)(out + (size_t)6 * NN);
        Sbf = Mbf + NN;
        p = out + (size_t)7 * NN;
        dd = p + NPTS;
    }

    zeroA_p_kernel<<<1024, 256, 0, stream>>>((float4*)A, feat, w_e1, b_e1, p, (float4*)dd);
    build_A_kernel<<<(NEDGE + 255) / 256, 256, 0, stream>>>(edges, edges + NEDGE, p, A, dd);
    normalize_kernel<<<NN / 4 / 256, 256, 0, stream>>>(A, dd, out, Mbf);

    dim3 grid(16, 16);
    gemm_S_kernel<<<grid, 512, 0, stream>>>(Mbf, Sbf, out);
    gemm_T34_kernel<<<grid, 512, 0, stream>>>(Mbf, Sbf, out, use_ws);

    if (!use_ws) {
        zero_kernel<<<(5 * NN / 4 + 255) / 256, 256, 0, stream>>>(
            (float4*)(out + (size_t)5 * NN), 5 * NN / 4);
    }
}